// Round 10
// baseline (375.085 us; speedup 1.0000x reference)
//
#include <hip/hip_runtime.h>
#include <hip/hip_bf16.h>
#include <math.h>

typedef __attribute__((ext_vector_type(8))) short short8;
typedef __attribute__((ext_vector_type(4))) short short4_;
typedef __attribute__((ext_vector_type(4))) float f32x4;

#define B_    32
#define C_    256
#define HW_   3136
#define N1_   768
#define NWIN_ 14
#define M_    100352   // B*HW

__device__ __forceinline__ short bf16_of(float f) {
  union { __hip_bfloat16 h; short s; } u;
  u.h = __float2bfloat16(f);
  return u.s;
}

__device__ __forceinline__ void load_lds16(const void* g, void* l) {
  __builtin_amdgcn_global_load_lds(
      (const __attribute__((address_space(1))) unsigned int*)g,
      (__attribute__((address_space(3))) unsigned int*)l, 16, 0, 0);
}

__device__ __forceinline__ f32x4 mfma16x16x16bf16(short4_ a, short4_ b, f32x4 c) {
#if __has_builtin(__builtin_amdgcn_mfma_f32_16x16x16bf16_1k)
  return __builtin_amdgcn_mfma_f32_16x16x16bf16_1k(a, b, c, 0, 0, 0);
#else
  asm volatile("v_mfma_f32_16x16x16_bf16 %0, %1, %2, %0\n\ts_nop 7\n\ts_nop 7"
               : "+v"(c) : "v"(a), "v"(b));
  return c;
#endif
}

// ---------------------------------------------------------------------------
// Kernel 0: weight conversion + QKV-column permutation (unchanged, verified).
// qkv channel order: n' = k*256 + h*32 + e  (orig n = 24e + 3h + k).
// ---------------------------------------------------------------------------
__global__ void conv_weights(const float* __restrict__ w1, const float* __restrict__ w2,
                             const float* __restrict__ b1,
                             short* __restrict__ w1p, short* __restrict__ w2b,
                             float* __restrict__ b1p) {
  int i = blockIdx.x * 256 + threadIdx.x;
  if (i < 196608) {
    const int r = i >> 8, c = i & 255;
    const int k = r >> 8, rem = r & 255, h = rem >> 5, e = rem & 31;
    const int orig = 24 * e + 3 * h + k;
    w1p[i] = bf16_of(w1[orig * 256 + c]);
  }
  if (i < 65536) w2b[i] = bf16_of(w2[i]);
  if (i < 768) {
    const int k = i >> 8, rem = i & 255, h = rem >> 5, e = rem & 31;
    b1p[i] = b1[24 * e + 3 * h + k];
  }
}

// ---------------------------------------------------------------------------
// Kernel 1: qkv GEMM with FUSED transpose+convert of x.
// A-tile (128m x 64k) staged per K-step straight from x[b][c][hw] f32:
// per-thread 4x4 register transpose (transpose_x's verified math) ->
// ds_write_b64 into the SAME As geometry the verified MFMA loop reads
// (128B rows, 16B-chunk XOR c^(r&7)). B side keeps global_load_lds.
// Saves the xt round-trip (102 MB) and one kernel.
// ---------------------------------------------------------------------------
__global__ __launch_bounds__(256) void qkv_gemm(const float* __restrict__ x,
    const short* __restrict__ w1p, const float* __restrict__ b1p,
    short* __restrict__ qkvb) {
  __shared__ char smem[32768];
  char* As = smem;
  char* Bs = smem + 16384;
  const int t = threadIdx.x, l = t & 63, w = t >> 6;
  const int d = blockIdx.x, xcd = d & 7, i0 = d >> 3;
  const int bn = i0 % 6, bm = (i0 / 6) * 8 + xcd;
  const int m0 = bm * 128, n0 = bn * 128;
  const int lane = l & 15, kg = l >> 4;
  const int wm = w >> 1, wn = w & 1;

  f32x4 acc[4][4];
#pragma unroll
  for (int i = 0; i < 4; ++i)
#pragma unroll
    for (int j = 0; j < 4; ++j) acc[i][j] = (f32x4){0.f, 0.f, 0.f, 0.f};

  for (int ks = 0; ks < 4; ++ks) {
    const int k0 = ks * 64;
    // B: async DMA first (fire-and-forget), unchanged from verified kernel
#pragma unroll
    for (int q = 0; q < 4; ++q) {
      const int row = (w * 4 + q) * 8 + (l >> 3);
      const int sc  = (l & 7) ^ (row & 7);
      load_lds16(w1p + (size_t)(n0 + row) * 256 + k0 + sc * 8, Bs + (w * 4 + q) * 1024);
    }
    // A: reg-staged transpose+convert from x. quad = 4m x 4k per thread-iter.
#pragma unroll
    for (int it = 0; it < 2; ++it) {
      const int qid = it * 256 + t;          // 0..511
      const int tm4 = qid & 31;              // m-quad (coalesced over lanes)
      const int tk4 = qid >> 5;              // k-quad 0..15
      const int m4g = m0 + tm4 * 4;
      const int bb = m4g / HW_;
      const int hw = m4g - bb * HW_;         // 4|3136 -> quad never crosses b
      const float* xp = x + ((size_t)bb * C_ + k0 + tk4 * 4) * HW_ + hw;
      float4 v0 = *(const float4*)(xp);
      float4 v1 = *(const float4*)(xp + HW_);
      float4 v2 = *(const float4*)(xp + 2 * HW_);
      float4 v3 = *(const float4*)(xp + 3 * HW_);
      const int c16 = tk4 >> 1, lo8 = (tk4 & 1) * 8;
#define WRA_(i2, e0, e1, e2, e3)                                       \
      { const int r = tm4 * 4 + i2;                                    \
        short4_ wv; wv[0] = bf16_of(e0); wv[1] = bf16_of(e1);          \
        wv[2] = bf16_of(e2); wv[3] = bf16_of(e3);                      \
        *(short4_*)(As + r * 128 + ((c16 ^ (r & 7)) << 4) + lo8) = wv; }
      WRA_(0, v0.x, v1.x, v2.x, v3.x)
      WRA_(1, v0.y, v1.y, v2.y, v3.y)
      WRA_(2, v0.z, v1.z, v2.z, v3.z)
      WRA_(3, v0.w, v1.w, v2.w, v3.w)
#undef WRA_
    }
    __syncthreads();
#pragma unroll
    for (int s = 0; s < 2; ++s) {
      short8 a[4], b[4];
#pragma unroll
      for (int i = 0; i < 4; ++i) {
        const int r = wm * 64 + i * 16 + lane;
        a[i] = *(const short8*)(As + r * 128 + ((s * 64 + kg * 16) ^ ((r & 7) << 4)));
      }
#pragma unroll
      for (int j = 0; j < 4; ++j) {
        const int r = wn * 64 + j * 16 + lane;
        b[j] = *(const short8*)(Bs + r * 128 + ((s * 64 + kg * 16) ^ ((r & 7) << 4)));
      }
#pragma unroll
      for (int i = 0; i < 4; ++i)
#pragma unroll
        for (int j = 0; j < 4; ++j)
          acc[i][j] = __builtin_amdgcn_mfma_f32_16x16x32_bf16(a[i], b[j], acc[i][j], 0, 0, 0);
    }
    __syncthreads();
  }

#pragma unroll
  for (int j = 0; j < 4; ++j) {
    const int n = n0 + wn * 64 + j * 16 + lane;
    const float bias = b1p[n];
#pragma unroll
    for (int i = 0; i < 4; ++i) {
      const int mb = m0 + wm * 64 + i * 16 + kg * 4;
#pragma unroll
      for (int r = 0; r < 4; ++r)
        qkvb[(size_t)(mb + r) * N1_ + n] = bf16_of(acc[i][j][r] + bias);
    }
  }
}

// ---------------------------------------------------------------------------
// Kernel 2: shifted-window attention + FUSED output projection.
// Attention path identical to the R9-verified kernel through the Ot build;
// then each wave computes out[16][h*32..+32] = Ot[16][256] @ w2^T + b2
// (A-frags from Ot, B-frags 16B loads from L2-resident w2b), f32 stores.
// Kills the attnb round-trip (102 MB) and the proj kernel.
// ---------------------------------------------------------------------------
__global__ __launch_bounds__(512) void win_attn(const short* __restrict__ qkvb,
    const float* __restrict__ pos, const short* __restrict__ w2b,
    const float* __restrict__ b2, float* __restrict__ out) {
  __shared__ __align__(16) short Sq[16 * 768];
  __shared__ __align__(16) short Ot[16 * 272];
  __shared__ float Pe[49];

  const int t = threadIdx.x, l = t & 63, h = t >> 6;
  if (t < 49) Pe[t] = pos[t];

  const int win = blockIdx.x;
  const int wxi = win % NWIN_;
  const int wyi = (win / NWIN_) % NWIN_;
  const int b   = win / (NWIN_ * NWIN_);

  // stage 16 shifted tokens' qkv rows (1536 B each), swizzled 16B chunks
#pragma unroll
  for (int rep = 0; rep < 3; ++rep) {
    const int idx = rep * 512 + t;
    const int row = idx / 96, ch = idx % 96;
    const int pr = row >> 2, pc = row & 3;
    int y  = wyi * 4 + pr + 2; if (y >= 56) y -= 56;
    int xx = wxi * 4 + pc + 2; if (xx >= 56) xx -= 56;
    const size_t m = (size_t)b * HW_ + y * 56 + xx;
    int4 v = *(const int4*)(qkvb + m * N1_ + ch * 8);
    *(int4*)(Sq + row * 768 + (ch ^ (row & 7)) * 8) = v;
  }
  __syncthreads();

  const int lane = l & 15, kg = l >> 4;

  // Q/K fragments: token = lane, e-slice kg*8..+8 -> one b128 each
  const int cQ = h * 4 + kg;
  short8 qf = *(const short8*)(Sq + lane * 768 + ((cQ)      ^ (lane & 7)) * 8);
  short8 kf = *(const short8*)(Sq + lane * 768 + ((32 + cQ) ^ (lane & 7)) * 8);

  f32x4 z = {0.f, 0.f, 0.f, 0.f};
  f32x4 st = __builtin_amdgcn_mfma_f32_16x16x32_bf16(kf, qf, z, 0, 0, 0);

  const int pr = lane >> 2, pc = lane & 3;
  const float rscale = 0.17677669529663687f;  // 1/sqrt(32)
  float sv[4];
#pragma unroll
  for (int r = 0; r < 4; ++r) {
    const int q = kg * 4 + r, qr = q >> 2, qc = q & 3;
    float s = st[r] * rscale + Pe[(qr - pr + 3) * 7 + (qc - pc + 3)];
    if (wyi == NWIN_ - 1 && ((pr >= 2) != (qr >= 2))) s = -1e30f;
    if (wxi == NWIN_ - 1 && ((pc >= 2) != (qc >= 2))) s = -1e30f;
    sv[r] = s;
  }
  float mx = fmaxf(fmaxf(sv[0], sv[1]), fmaxf(sv[2], sv[3]));
  mx = fmaxf(mx, __shfl_xor(mx, 16));
  mx = fmaxf(mx, __shfl_xor(mx, 32));
  float ex[4], sm = 0.f;
#pragma unroll
  for (int r = 0; r < 4; ++r) { ex[r] = __expf(sv[r] - mx); sm += ex[r]; }
  sm += __shfl_xor(sm, 16);
  sm += __shfl_xor(sm, 32);
  const float inv = 1.0f / sm;
  short4_ pf;
#pragma unroll
  for (int r = 0; r < 4; ++r) pf[r] = bf16_of(ex[r] * inv);

  // PV: V[token=kg*4+i][e = half*16+lane]
#pragma unroll
  for (int half = 0; half < 2; ++half) {
    short4_ vf;
    const int cV = 64 + h * 4 + half * 2 + (lane >> 3);   // 16B chunk
    const int el = lane & 7;
#pragma unroll
    for (int i = 0; i < 4; ++i) {
      const int vrow = kg * 4 + i;
      vf[i] = Sq[vrow * 768 + (cV ^ (vrow & 7)) * 8 + el];
    }
    f32x4 o = mfma16x16x16bf16(pf, vf, z);
#pragma unroll
    for (int r = 0; r < 4; ++r)
      Ot[(kg * 4 + r) * 272 + h * 32 + half * 16 + lane] = bf16_of(o[r]);
  }
  __syncthreads();   // Ot complete across all 8 heads

  // ---- fused projection: wave h computes out[16][h*32..h*32+32) ----
  f32x4 pacc0 = z, pacc1 = z;
  const int n0p = h * 32;
#pragma unroll
  for (int ksp = 0; ksp < 8; ++ksp) {
    const int koff = ksp * 32 + kg * 8;
    short8 af  = *(const short8*)(Ot + lane * 272 + koff);
    short8 bf0 = *(const short8*)(w2b + (size_t)(n0p + lane) * 256 + koff);
    short8 bf1 = *(const short8*)(w2b + (size_t)(n0p + 16 + lane) * 256 + koff);
    pacc0 = __builtin_amdgcn_mfma_f32_16x16x32_bf16(af, bf0, pacc0, 0, 0, 0);
    pacc1 = __builtin_amdgcn_mfma_f32_16x16x32_bf16(af, bf1, pacc1, 0, 0, 0);
  }
  const int ncol = n0p + lane;
  const float bias0 = b2[ncol], bias1 = b2[ncol + 16];
#pragma unroll
  for (int r = 0; r < 4; ++r) {
    const int m = kg * 4 + r;   // window token index (C/D row)
    const size_t mo = (size_t)b * HW_ + (wyi * 4 + (m >> 2)) * 56 + wxi * 4 + (m & 3);
    out[mo * C_ + ncol]      = pacc0[r] + bias0;
    out[mo * C_ + ncol + 16] = pacc1[r] + bias1;
  }
}

// ---------------------------------------------------------------------------
extern "C" void kernel_launch(void* const* d_in, const int* in_sizes, int n_in,
                              void* d_out, int out_size, void* d_ws, size_t ws_size,
                              hipStream_t stream) {
  const float* x   = (const float*)d_in[0];
  const float* w1  = (const float*)d_in[1];
  const float* b1  = (const float*)d_in[2];
  const float* w2  = (const float*)d_in[3];
  const float* b2  = (const float*)d_in[4];
  const float* pos = (const float*)d_in[5];
  float* out = (float*)d_out;

  char* ws = (char*)d_ws;
  short* qkvb = (short*)ws;                        // 100352*768 bf16 (154.1 MB)
  short* w1p  = (short*)(ws + (size_t)155000000);  // 196608 bf16
  short* w2b  = w1p + 196608;                      // 65536 bf16
  float* b1p  = (float*)(w2b + 65536);             // 768 f32

  conv_weights<<<768, 256, 0, stream>>>(w1, w2, b1, w1p, w2b, b1p);
  qkv_gemm    <<<4704, 256, 0, stream>>>(x, w1p, b1p, qkvb);
  win_attn    <<<6272, 512, 0, stream>>>(qkvb, pos, w2b, b2, out);
}

// Round 11
// 367.276 us; speedup vs baseline: 1.0213x; 1.0213x over previous
//
#include <hip/hip_runtime.h>
#include <hip/hip_bf16.h>
#include <math.h>

typedef __attribute__((ext_vector_type(8))) short short8;
typedef __attribute__((ext_vector_type(4))) short short4_;
typedef __attribute__((ext_vector_type(4))) float f32x4;

#define B_    32
#define C_    256
#define HW_   3136
#define N1_   768
#define NWIN_ 14
#define M_    100352   // B*HW

__device__ __forceinline__ short bf16_of(float f) {
  union { __hip_bfloat16 h; short s; } u;
  u.h = __float2bfloat16(f);
  return u.s;
}

__device__ __forceinline__ void load_lds16(const void* g, void* l) {
  __builtin_amdgcn_global_load_lds(
      (const __attribute__((address_space(1))) unsigned int*)g,
      (__attribute__((address_space(3))) unsigned int*)l, 16, 0, 0);
}

__device__ __forceinline__ f32x4 mfma16x16x16bf16(short4_ a, short4_ b, f32x4 c) {
#if __has_builtin(__builtin_amdgcn_mfma_f32_16x16x16bf16_1k)
  return __builtin_amdgcn_mfma_f32_16x16x16bf16_1k(a, b, c, 0, 0, 0);
#else
  asm volatile("v_mfma_f32_16x16x16_bf16 %0, %1, %2, %0\n\ts_nop 7\n\ts_nop 7"
               : "+v"(c) : "v"(a), "v"(b));
  return c;
#endif
}

// ---------------------------------------------------------------------------
// Kernel 0: weight conversion + QKV-column permutation (unchanged, verified).
// qkv channel order: n' = k*256 + h*32 + e  (orig n = 24e + 3h + k).
// ---------------------------------------------------------------------------
__global__ void conv_weights(const float* __restrict__ w1, const float* __restrict__ w2,
                             const float* __restrict__ b1,
                             short* __restrict__ w1p, short* __restrict__ w2b,
                             float* __restrict__ b1p) {
  int i = blockIdx.x * 256 + threadIdx.x;
  if (i < 196608) {
    const int r = i >> 8, c = i & 255;
    const int k = r >> 8, rem = r & 255, h = rem >> 5, e = rem & 31;
    const int orig = 24 * e + 3 * h + k;
    w1p[i] = bf16_of(w1[orig * 256 + c]);
  }
  if (i < 65536) w2b[i] = bf16_of(w2[i]);
  if (i < 768) {
    const int k = i >> 8, rem = i & 255, h = rem >> 5, e = rem & 31;
    b1p[i] = b1[24 * e + 3 * h + k];
  }
}

// ---------------------------------------------------------------------------
// Kernel 1: qkv GEMM with fused transpose+convert of x.
// R11 change (only change this round): A-buffer chunk-XOR is ((r>>2)&7)
// on BOTH write and read sides (was (r&7)).
//   - write instant i2: rows r=4*tm4+i2 -> (r>>2)&7 = tm4&7 spans 0..7
//     across lanes -> banks uniform -> conflict-free ds_write_b64
//     (was ~16-way: stride-4 rows on 128B pitch gave only 2 chunk slots).
//   - read: positions collapse 8->4 slots -> ~2x on the 8 A-reads; net
//     ~-160 cyc/wave/K-step.  B-buffer keeps (r&7) (DMA write, free read).
// ---------------------------------------------------------------------------
__global__ __launch_bounds__(256) void qkv_gemm(const float* __restrict__ x,
    const short* __restrict__ w1p, const float* __restrict__ b1p,
    short* __restrict__ qkvb) {
  __shared__ char smem[32768];
  char* As = smem;
  char* Bs = smem + 16384;
  const int t = threadIdx.x, l = t & 63, w = t >> 6;
  const int d = blockIdx.x, xcd = d & 7, i0 = d >> 3;
  const int bn = i0 % 6, bm = (i0 / 6) * 8 + xcd;
  const int m0 = bm * 128, n0 = bn * 128;
  const int lane = l & 15, kg = l >> 4;
  const int wm = w >> 1, wn = w & 1;

  f32x4 acc[4][4];
#pragma unroll
  for (int i = 0; i < 4; ++i)
#pragma unroll
    for (int j = 0; j < 4; ++j) acc[i][j] = (f32x4){0.f, 0.f, 0.f, 0.f};

  for (int ks = 0; ks < 4; ++ks) {
    const int k0 = ks * 64;
    // B: async DMA first (fire-and-forget), unchanged
#pragma unroll
    for (int q = 0; q < 4; ++q) {
      const int row = (w * 4 + q) * 8 + (l >> 3);
      const int sc  = (l & 7) ^ (row & 7);
      load_lds16(w1p + (size_t)(n0 + row) * 256 + k0 + sc * 8, Bs + (w * 4 + q) * 1024);
    }
    // A: reg-staged transpose+convert from x; quad = 4m x 4k per thread-iter
#pragma unroll
    for (int it = 0; it < 2; ++it) {
      const int qid = it * 256 + t;          // 0..511
      const int tm4 = qid & 31;              // m-quad (coalesced over lanes)
      const int tk4 = qid >> 5;              // k-quad 0..15
      const int m4g = m0 + tm4 * 4;
      const int bb = m4g / HW_;
      const int hw = m4g - bb * HW_;         // 4|3136 -> quad never crosses b
      const float* xp = x + ((size_t)bb * C_ + k0 + tk4 * 4) * HW_ + hw;
      float4 v0 = *(const float4*)(xp);
      float4 v1 = *(const float4*)(xp + HW_);
      float4 v2 = *(const float4*)(xp + 2 * HW_);
      float4 v3 = *(const float4*)(xp + 3 * HW_);
      const int c16 = tk4 >> 1, lo8 = (tk4 & 1) * 8;
#define WRA_(i2, e0, e1, e2, e3)                                       \
      { const int r = tm4 * 4 + i2;                                    \
        short4_ wv; wv[0] = bf16_of(e0); wv[1] = bf16_of(e1);          \
        wv[2] = bf16_of(e2); wv[3] = bf16_of(e3);                      \
        *(short4_*)(As + r * 128 + ((c16 ^ ((r >> 2) & 7)) << 4) + lo8) = wv; }
      WRA_(0, v0.x, v1.x, v2.x, v3.x)
      WRA_(1, v0.y, v1.y, v2.y, v3.y)
      WRA_(2, v0.z, v1.z, v2.z, v3.z)
      WRA_(3, v0.w, v1.w, v2.w, v3.w)
#undef WRA_
    }
    __syncthreads();
#pragma unroll
    for (int s = 0; s < 2; ++s) {
      short8 a[4], b[4];
#pragma unroll
      for (int i = 0; i < 4; ++i) {
        const int r = wm * 64 + i * 16 + lane;
        a[i] = *(const short8*)(As + r * 128 + ((s * 64 + kg * 16) ^ (((r >> 2) & 7) << 4)));
      }
#pragma unroll
      for (int j = 0; j < 4; ++j) {
        const int r = wn * 64 + j * 16 + lane;
        b[j] = *(const short8*)(Bs + r * 128 + ((s * 64 + kg * 16) ^ ((r & 7) << 4)));
      }
#pragma unroll
      for (int i = 0; i < 4; ++i)
#pragma unroll
        for (int j = 0; j < 4; ++j)
          acc[i][j] = __builtin_amdgcn_mfma_f32_16x16x32_bf16(a[i], b[j], acc[i][j], 0, 0, 0);
    }
    __syncthreads();
  }

#pragma unroll
  for (int j = 0; j < 4; ++j) {
    const int n = n0 + wn * 64 + j * 16 + lane;
    const float bias = b1p[n];
#pragma unroll
    for (int i = 0; i < 4; ++i) {
      const int mb = m0 + wm * 64 + i * 16 + kg * 4;
#pragma unroll
      for (int r = 0; r < 4; ++r)
        qkvb[(size_t)(mb + r) * N1_ + n] = bf16_of(acc[i][j][r] + bias);
    }
  }
}

// ---------------------------------------------------------------------------
// Kernel 2: shifted-window attention + fused output projection (unchanged
// from R10-verified).
// ---------------------------------------------------------------------------
__global__ __launch_bounds__(512) void win_attn(const short* __restrict__ qkvb,
    const float* __restrict__ pos, const short* __restrict__ w2b,
    const float* __restrict__ b2, float* __restrict__ out) {
  __shared__ __align__(16) short Sq[16 * 768];
  __shared__ __align__(16) short Ot[16 * 272];
  __shared__ float Pe[49];

  const int t = threadIdx.x, l = t & 63, h = t >> 6;
  if (t < 49) Pe[t] = pos[t];

  const int win = blockIdx.x;
  const int wxi = win % NWIN_;
  const int wyi = (win / NWIN_) % NWIN_;
  const int b   = win / (NWIN_ * NWIN_);

  // stage 16 shifted tokens' qkv rows (1536 B each), swizzled 16B chunks
#pragma unroll
  for (int rep = 0; rep < 3; ++rep) {
    const int idx = rep * 512 + t;
    const int row = idx / 96, ch = idx % 96;
    const int pr = row >> 2, pc = row & 3;
    int y  = wyi * 4 + pr + 2; if (y >= 56) y -= 56;
    int xx = wxi * 4 + pc + 2; if (xx >= 56) xx -= 56;
    const size_t m = (size_t)b * HW_ + y * 56 + xx;
    int4 v = *(const int4*)(qkvb + m * N1_ + ch * 8);
    *(int4*)(Sq + row * 768 + (ch ^ (row & 7)) * 8) = v;
  }
  __syncthreads();

  const int lane = l & 15, kg = l >> 4;

  // Q/K fragments: token = lane, e-slice kg*8..+8 -> one b128 each
  const int cQ = h * 4 + kg;
  short8 qf = *(const short8*)(Sq + lane * 768 + ((cQ)      ^ (lane & 7)) * 8);
  short8 kf = *(const short8*)(Sq + lane * 768 + ((32 + cQ) ^ (lane & 7)) * 8);

  f32x4 z = {0.f, 0.f, 0.f, 0.f};
  f32x4 st = __builtin_amdgcn_mfma_f32_16x16x32_bf16(kf, qf, z, 0, 0, 0);

  const int pr = lane >> 2, pc = lane & 3;
  const float rscale = 0.17677669529663687f;  // 1/sqrt(32)
  float sv[4];
#pragma unroll
  for (int r = 0; r < 4; ++r) {
    const int q = kg * 4 + r, qr = q >> 2, qc = q & 3;
    float s = st[r] * rscale + Pe[(qr - pr + 3) * 7 + (qc - pc + 3)];
    if (wyi == NWIN_ - 1 && ((pr >= 2) != (qr >= 2))) s = -1e30f;
    if (wxi == NWIN_ - 1 && ((pc >= 2) != (qc >= 2))) s = -1e30f;
    sv[r] = s;
  }
  float mx = fmaxf(fmaxf(sv[0], sv[1]), fmaxf(sv[2], sv[3]));
  mx = fmaxf(mx, __shfl_xor(mx, 16));
  mx = fmaxf(mx, __shfl_xor(mx, 32));
  float ex[4], sm = 0.f;
#pragma unroll
  for (int r = 0; r < 4; ++r) { ex[r] = __expf(sv[r] - mx); sm += ex[r]; }
  sm += __shfl_xor(sm, 16);
  sm += __shfl_xor(sm, 32);
  const float inv = 1.0f / sm;
  short4_ pf;
#pragma unroll
  for (int r = 0; r < 4; ++r) pf[r] = bf16_of(ex[r] * inv);

  // PV: V[token=kg*4+i][e = half*16+lane]
#pragma unroll
  for (int half = 0; half < 2; ++half) {
    short4_ vf;
    const int cV = 64 + h * 4 + half * 2 + (lane >> 3);   // 16B chunk
    const int el = lane & 7;
#pragma unroll
    for (int i = 0; i < 4; ++i) {
      const int vrow = kg * 4 + i;
      vf[i] = Sq[vrow * 768 + (cV ^ (vrow & 7)) * 8 + el];
    }
    f32x4 o = mfma16x16x16bf16(pf, vf, z);
#pragma unroll
    for (int r = 0; r < 4; ++r)
      Ot[(kg * 4 + r) * 272 + h * 32 + half * 16 + lane] = bf16_of(o[r]);
  }
  __syncthreads();   // Ot complete across all 8 heads

  // ---- fused projection: wave h computes out[16][h*32..h*32+32) ----
  f32x4 pacc0 = z, pacc1 = z;
  const int n0p = h * 32;
#pragma unroll
  for (int ksp = 0; ksp < 8; ++ksp) {
    const int koff = ksp * 32 + kg * 8;
    short8 af  = *(const short8*)(Ot + lane * 272 + koff);
    short8 bf0 = *(const short8*)(w2b + (size_t)(n0p + lane) * 256 + koff);
    short8 bf1 = *(const short8*)(w2b + (size_t)(n0p + 16 + lane) * 256 + koff);
    pacc0 = __builtin_amdgcn_mfma_f32_16x16x32_bf16(af, bf0, pacc0, 0, 0, 0);
    pacc1 = __builtin_amdgcn_mfma_f32_16x16x32_bf16(af, bf1, pacc1, 0, 0, 0);
  }
  const int ncol = n0p + lane;
  const float bias0 = b2[ncol], bias1 = b2[ncol + 16];
#pragma unroll
  for (int r = 0; r < 4; ++r) {
    const int m = kg * 4 + r;   // window token index (C/D row)
    const size_t mo = (size_t)b * HW_ + (wyi * 4 + (m >> 2)) * 56 + wxi * 4 + (m & 3);
    out[mo * C_ + ncol]      = pacc0[r] + bias0;
    out[mo * C_ + ncol + 16] = pacc1[r] + bias1;
  }
}

// ---------------------------------------------------------------------------
extern "C" void kernel_launch(void* const* d_in, const int* in_sizes, int n_in,
                              void* d_out, int out_size, void* d_ws, size_t ws_size,
                              hipStream_t stream) {
  const float* x   = (const float*)d_in[0];
  const float* w1  = (const float*)d_in[1];
  const float* b1  = (const float*)d_in[2];
  const float* w2  = (const float*)d_in[3];
  const float* b2  = (const float*)d_in[4];
  const float* pos = (const float*)d_in[5];
  float* out = (float*)d_out;

  char* ws = (char*)d_ws;
  short* qkvb = (short*)ws;                        // 100352*768 bf16 (154.1 MB)
  short* w1p  = (short*)(ws + (size_t)155000000);  // 196608 bf16
  short* w2b  = w1p + 196608;                      // 65536 bf16
  float* b1p  = (float*)(w2b + 65536);             // 768 f32

  conv_weights<<<768, 256, 0, stream>>>(w1, w2, b1, w1p, w2b, b1p);
  qkv_gemm    <<<4704, 256, 0, stream>>>(x, w1p, b1p, qkvb);
  win_attn    <<<6272, 512, 0, stream>>>(qkvb, pos, w2b, b2, out);
}